// Round 9
// baseline (709.168 us; speedup 1.0000x reference)
//
#include <hip/hip_runtime.h>
#include <math.h>

#define N_CELLS 1024
#define HID     256
#define N_LOOP  32
#define FLAT    (N_CELLS*HID)   // 262144

#define GRIDF   4384            // 4096 gen + 288 specials
#define NSPEC   288             // 256 disc (2 rows each) + 32 chain

typedef float f4 __attribute__((ext_vector_type(4)));

__device__ __forceinline__ float wave_reduce64(float v) {
    #pragma unroll
    for (int m = 32; m; m >>= 1) v += __shfl_xor(v, m);
    return v;
}
__device__ __forceinline__ float dot4(float4 a, float4 b) {
    return a.x*b.x + a.y*b.y + a.z*b.z + a.w*b.w;
}
__device__ __forceinline__ float dot4v(f4 a, float4 b) {
    return a.x*b.x + a.y*b.y + a.z*b.z + a.w*b.w;
}

#define ALD(p)   __hip_atomic_load((p), __ATOMIC_RELAXED, __HIP_MEMORY_SCOPE_AGENT)
#define AST(p,v) __hip_atomic_store((p), (v), __ATOMIC_RELAXED, __HIP_MEMORY_SCOPE_AGENT)

// ============ h1 = relu(W1.gi + b1) (also zeroes control words) ============
__global__ void k_gen_h1(const float* __restrict__ x, const float* __restrict__ noise,
                         const float* __restrict__ W1, const float* __restrict__ b1,
                         float* __restrict__ h1, unsigned int* __restrict__ ctrl) {
    __shared__ __align__(16) float gi[288];
    int t = threadIdx.x, l = t & 63, w = t >> 6;
    if (blockIdx.x == 0 && t < 64) ctrl[t] = 0u;   // fcnt[0..7] @0, fflag[0..7] @32
    gi[t] = x[t];
    if (t < 32) gi[256 + t] = noise[t];
    __syncthreads();
    int j = blockIdx.x * 4 + w;
    const float4* wr = (const float4*)(W1 + j * 288);
    const float4* g4 = (const float4*)gi;
    float acc = dot4(wr[l], g4[l]);
    if (l < 8) acc += dot4(wr[64 + l], g4[64 + l]);
    acc = wave_reduce64(acc);
    if (l == 0) h1[j] = fmaxf(acc + b1[j], 0.f);
}

// ============ h2 = relu(W2.h1 + b2) ============
__global__ void k_gen_h2(const float* __restrict__ h1, const float* __restrict__ W2,
                         const float* __restrict__ b2, float* __restrict__ h2) {
    int t = threadIdx.x, l = t & 63, w = t >> 6;
    int j = blockIdx.x * 4 + w;
    float acc = dot4(((const float4*)(W2 + j * 256))[l], ((const float4*)h1)[l]);
    acc = wave_reduce64(acc);
    if (l == 0) h2[j] = fmaxf(acc + b2[j], 0.f);
}

// ============ FUSED: gen(+fmean) producer / disc+chain consumers ============
__global__ void __launch_bounds__(1024, 8)
k_fused(const float* __restrict__ W3, const float* __restrict__ b3,
        const float* __restrict__ h2,
        const float* __restrict__ dW1, const float* __restrict__ db1,
        const float* __restrict__ ch, const int* __restrict__ step,
        const float* __restrict__ x,
        const float* __restrict__ eaW1, const float* __restrict__ eab1,
        const float* __restrict__ eaW2, const float* __restrict__ eab2,
        const float* __restrict__ egW1, const float* __restrict__ egb1,
        const float* __restrict__ egW2, const float* __restrict__ egb2,
        const float* __restrict__ Wih, const float* __restrict__ bih,
        const float* __restrict__ Whh, const float* __restrict__ bhh,
        float* __restrict__ gs, float* __restrict__ fmean,
        unsigned int* __restrict__ ctrl,
        float* __restrict__ d1r, float* __restrict__ d1f,
        float* __restrict__ outputs, float* __restrict__ tensions,
        float* __restrict__ out) {
    // ---- shared (all roles; sums fit 2 blocks/CU) ----
    __shared__ __align__(16) float fmL[2048];
    __shared__ __align__(16) float gmL[256];
    __shared__ __align__(16) float swl[4096];
    __shared__ float swS[256];
    __shared__ float sA[16], sB[16], sC[16], sD[16];
    __shared__ float sS[2];
    __shared__ __align__(16) float fm_part[1024];
    __shared__ int lastS;
    __shared__ __align__(16) float xL[256];
    __shared__ __align__(16) float vf[256];
    __shared__ float Hacc[256];
    __shared__ float E[256];
    __shared__ float Ghh[768];
    __shared__ __align__(16) float hag[256];
    __shared__ __align__(16) float outs[256];
    __shared__ float red[256];
    __shared__ float gihL[768];
    __shared__ float tsh;

    unsigned int* fcnt  = ctrl;
    unsigned int* fflag = ctrl + 32;
    int b = blockIdx.x, t = threadIdx.x, l = t & 63, w = t >> 6;
    bool deb = (*step > 5);

    int s = -1;
    if ((b % 15) == 0 && (b / 15) < NSPEC) s = b / 15;

    if (s < 0) {
        // ================= GEN role =================
        int nb = (b == 0) ? 0 : ((b - 1) / 15 + 1);
        if (nb > NSPEC) nb = NSPEC;
        int g = b - nb;                       // 0..4095
        int fct = g >> 9;                     // 512 gen blocks per faction
        int r0 = g * 64 + w * 4;
        const float4* h24 = (const float4*)h2;
        float4 ha = h24[l], hb = h24[64 + l];
        const f4* w0p = (const f4*)(W3 + (size_t)(r0 + 0) * 512);
        const f4* w1p = (const f4*)(W3 + (size_t)(r0 + 1) * 512);
        const f4* w2p = (const f4*)(W3 + (size_t)(r0 + 2) * 512);
        const f4* w3p = (const f4*)(W3 + (size_t)(r0 + 3) * 512);
        f4 A0 = __builtin_nontemporal_load(w0p + l), B0 = __builtin_nontemporal_load(w0p + 64 + l);
        f4 A1 = __builtin_nontemporal_load(w1p + l), B1 = __builtin_nontemporal_load(w1p + 64 + l);
        f4 A2 = __builtin_nontemporal_load(w2p + l), B2 = __builtin_nontemporal_load(w2p + 64 + l);
        f4 A3 = __builtin_nontemporal_load(w3p + l), B3 = __builtin_nontemporal_load(w3p + 64 + l);
        float s0 = dot4v(A0, ha) + dot4v(B0, hb);
        float s1 = dot4v(A1, ha) + dot4v(B1, hb);
        float s2 = dot4v(A2, ha) + dot4v(B2, hb);
        float s3 = dot4v(A3, ha) + dot4v(B3, hb);
        s0 = wave_reduce64(s0); s1 = wave_reduce64(s1);
        s2 = wave_reduce64(s2); s3 = wave_reduce64(s3);
        if (l < 4) {
            float sv = (l == 0) ? s0 : (l == 1) ? s1 : (l == 2) ? s2 : s3;
            AST(gs + r0 + l, sv + b3[r0 + l]);
        }
        __syncthreads();
        if (t == 0)
            lastS = (__hip_atomic_fetch_add(&fcnt[fct], 1u, __ATOMIC_ACQ_REL,
                                            __HIP_MEMORY_SCOPE_AGENT) == 511u);
        __syncthreads();
        if (lastS) {
            // this block computes fmean[fct]
            int d = t & 255, q = t >> 8;
            const float* basep = gs + fct * 32768 + q * 8192 + d;
            float sum = 0.f;
            for (int r = 0; r < 32; ++r) sum += ALD(basep + r * 256);
            fm_part[t] = sum;
            __syncthreads();
            if (t < 256) {
                float v = (fm_part[t] + fm_part[256 + t] + fm_part[512 + t] + fm_part[768 + t])
                          * (1.f / 128.f);
                AST(fmean + fct * 256 + t, v);
            }
            __syncthreads();
            if (t == 0)
                __hip_atomic_store(&fflag[fct], 1u, __ATOMIC_RELEASE, __HIP_MEMORY_SCOPE_AGENT);
        }
        return;
    }

    if (s < 256) {
        // ================= DISC role: rows 2s, 2s+1 =================
        int row0 = 2 * s, row1 = 2 * s + 1;
        const f4* wr0 = (const f4*)dW1 + (size_t)row0 * 65536;
        const f4* wr1 = (const f4*)dW1 + (size_t)row1 * 65536;
        const float4* c4 = (const float4*)ch;
        float aR0 = 0.f, aF0 = 0.f, aR1 = 0.f, aF1 = 0.f;
        f4 SW0 = {0.f, 0.f, 0.f, 0.f}, SW1 = {0.f, 0.f, 0.f, 0.f};
        for (int f = 0; f < 8; ++f) {
            if (t == 0) {
                while (__hip_atomic_load(&fflag[f], __ATOMIC_ACQUIRE,
                                         __HIP_MEMORY_SCOPE_AGENT) == 0u)
                    __builtin_amdgcn_s_sleep(16);
            }
            __syncthreads();
            if (t < 256) fmL[f * 256 + t] = ALD(fmean + f * 256 + t);
            __syncthreads();
            int base = f * 8192;
            #pragma unroll 2
            for (int k2 = 0; k2 < 8; ++k2) {
                int i = base + k2 * 1024 + t;
                f4 ww0 = __builtin_nontemporal_load(wr0 + i);
                f4 ww1 = __builtin_nontemporal_load(wr1 + i);
                const float* gp = gs + 4 * (size_t)i;
                float g0 = ALD(gp + 0), g1 = ALD(gp + 1), g2 = ALD(gp + 2), g3 = ALD(gp + 3);
                float4 cv = c4[i];
                f4 fmv = ((const f4*)fmL)[(f << 6) + (i & 63)];
                bool debate = deb && (((i >> 6) & 127) < 32);
                float cg = debate ? 0.50575f : 0.595f;
                float cf = debate ? 0.08925f : 0.105f;
                float dg0 = ww0.x*g0 + ww0.y*g1 + ww0.z*g2 + ww0.w*g3;
                float df0 = ww0.x*fmv.x + ww0.y*fmv.y + ww0.z*fmv.z + ww0.w*fmv.w;
                float dc0 = ww0.x*cv.x + ww0.y*cv.y + ww0.z*cv.z + ww0.w*cv.w;
                aR0 += cg*dg0 + cf*df0 + 0.3f*dc0;  aF0 += dg0;
                float dg1 = ww1.x*g0 + ww1.y*g1 + ww1.z*g2 + ww1.w*g3;
                float df1 = ww1.x*fmv.x + ww1.y*fmv.y + ww1.z*fmv.z + ww1.w*fmv.w;
                float dc1 = ww1.x*cv.x + ww1.y*cv.y + ww1.z*cv.z + ww1.w*cv.w;
                aR1 += cg*dg1 + cf*df1 + 0.3f*dc1;  aF1 += dg1;
                if (debate) { SW0 += ww0; SW1 += ww1; }
            }
        }
        // gm
        __syncthreads();
        if (t < 256) {
            float gsum = 0.f;
            #pragma unroll
            for (int f = 0; f < 8; ++f) gsum += fmL[f * 256 + t];
            gmL[t] = gsum * 0.125f;
        }
        __syncthreads();
        // SW reductions (row0 then row1)
        ((f4*)swl)[w * 64 + l] = SW0;
        __syncthreads();
        if (t < 256) {
            float sv = 0.f;
            #pragma unroll
            for (int q = 0; q < 16; ++q) sv += swl[q * 256 + t];
            swS[t] = sv * gmL[t];
        }
        __syncthreads();
        for (int m = 128; m; m >>= 1) { if (t < m) swS[t] += swS[t + m]; __syncthreads(); }
        if (t == 0) sS[0] = swS[0];
        __syncthreads();
        ((f4*)swl)[w * 64 + l] = SW1;
        __syncthreads();
        if (t < 256) {
            float sv = 0.f;
            #pragma unroll
            for (int q = 0; q < 16; ++q) sv += swl[q * 256 + t];
            swS[t] = sv * gmL[t];
        }
        __syncthreads();
        for (int m = 128; m; m >>= 1) { if (t < m) swS[t] += swS[t + m]; __syncthreads(); }
        if (t == 0) sS[1] = swS[0];
        __syncthreads();
        // accumulate the four dot totals
        aR0 = wave_reduce64(aR0); aF0 = wave_reduce64(aF0);
        aR1 = wave_reduce64(aR1); aF1 = wave_reduce64(aF1);
        if (l == 0) { sA[w] = aR0; sB[w] = aF0; sC[w] = aR1; sD[w] = aF1; }
        __syncthreads();
        if (t < 16) {
            float a = sA[t], bb = sB[t], c = sC[t], dd = sD[t];
            #pragma unroll
            for (int m = 8; m; m >>= 1) {
                a += __shfl_xor(a, m); bb += __shfl_xor(bb, m);
                c += __shfl_xor(c, m); dd += __shfl_xor(dd, m);
            }
            if (t == 0) {
                d1r[row0] = a + 0.105f * sS[0] + db1[row0];
                d1f[row0] = bb + db1[row0];
                d1r[row1] = c + 0.105f * sS[1] + db1[row1];
                d1f[row1] = dd + db1[row1];
            }
        }
        return;
    }

    // ================= CHAIN role: sample i = s-256 =================
    {
        int i = s - 256;
        if (t < 256) { xL[t] = x[t]; Hacc[t] = 0.f; }
        for (int j2 = t; j2 < 768; j2 += 1024) Ghh[j2] = 0.f;
        __syncthreads();
        // phase A: E[j] = Wa_j . x  (no dependencies)
        for (int k = 0; k < 16; ++k) {
            int j = w * 16 + k;
            const float* Wp = (j < 128) ? (eaW1 + (size_t)j * 512)
                                        : (egW1 + (size_t)(j - 128) * 512);
            float acc = dot4(((const float4*)Wp)[l], ((const float4*)xL)[l]);
            acc = wave_reduce64(acc);
            if (l == 0) E[j] = acc;
        }
        int nf = deb ? 8 : 1;
        for (int f = 0; f < nf; ++f) {
            if (t == 0) {
                while (__hip_atomic_load(&fflag[f], __ATOMIC_ACQUIRE,
                                         __HIP_MEMORY_SCOPE_AGENT) == 0u)
                    __builtin_amdgcn_s_sleep(16);
            }
            __syncthreads();
            if (t < 256) {
                float fmv = ALD(fmean + f * 256 + t);
                float v;
                if (f == 0) {
                    float gsv = ALD(gs + i * 256 + t);
                    v = deb ? (0.7225f * gsv + 0.14625f * fmv)
                            : (0.85f * gsv + 0.15f * fmv);
                } else {
                    v = 0.01875f * fmv;
                }
                vf[t] = v;
                Hacc[t] += v;
            }
            __syncthreads();
            // E += Wb . vf
            for (int k = 0; k < 16; ++k) {
                int j = w * 16 + k;
                const float* Wp = (j < 128) ? (eaW1 + (size_t)j * 512 + 256)
                                            : (egW1 + (size_t)(j - 128) * 512 + 256);
                float acc = dot4(((const float4*)Wp)[l], ((const float4*)vf)[l]);
                acc = wave_reduce64(acc);
                if (l == 0) E[j] += acc;
            }
            // Ghh += Whh . vf
            for (int k = 0; k < 48; ++k) {
                int u = w * 48 + k;
                float acc = dot4(((const float4*)(Whh + (size_t)u * 256))[l],
                                 ((const float4*)vf)[l]);
                acc = wave_reduce64(acc);
                if (l == 0) Ghh[u] += acc;
            }
            __syncthreads();
        }
        // relu(E + bias)
        if (t < 256) {
            float e = E[t] + ((t < 128) ? eab1[t] : egb1[t - 128]);
            hag[t] = fmaxf(e, 0.f);
        }
        __syncthreads();
        // ev2: outputs = a - g
        for (int k = 0; k < 16; ++k) {
            int tr = w * 16 + k;
            int sl = l & 31;
            bool lo = (l < 32);
            const float4* wv4 = lo ? (const float4*)(eaW2 + (size_t)tr * 128)
                                   : (const float4*)(egW2 + (size_t)tr * 128);
            const float4* h4 = (const float4*)(hag + (lo ? 0 : 128));
            float d_ = dot4(wv4[sl], h4[sl]);
            float acc = lo ? d_ : -d_;
            acc = wave_reduce64(acc);
            if (l == 0) {
                float o = acc + eab2[tr] - egb2[tr];
                outs[tr] = o;
                outputs[i * 256 + tr] = o;
            }
        }
        __syncthreads();
        if (t < 256) red[t] = outs[t] * outs[t];
        __syncthreads();
        for (int m = 128; m; m >>= 1) { if (t < m) red[t] += red[t + m]; __syncthreads(); }
        if (t == 0) { float tn = red[0] * (1.f / 256.f); tensions[i] = tn; tsh = tn; }
        __syncthreads();
        float tn = tsh;
        // gih = Wih . [outs | tn] + bih
        {
            float4 ov = ((const float4*)outs)[l];
            for (int k = 0; k < 48; ++k) {
                int u = w * 48 + k;
                const float* wr = Wih + (size_t)u * 257;
                float g0 = wr[4*l]*ov.x + wr[4*l+1]*ov.y + wr[4*l+2]*ov.z + wr[4*l+3]*ov.w;
                if (l == 0) g0 += wr[256] * tn;
                g0 = wave_reduce64(g0);
                if (l == 0) gihL[u] = g0 + bih[u];
            }
        }
        __syncthreads();
        if (t < 256) {
            float rr = 1.f / (1.f + expf(-(gihL[t] + Ghh[t] + bhh[t])));
            float zz = 1.f / (1.f + expf(-(gihL[256 + t] + Ghh[256 + t] + bhh[256 + t])));
            float ncand = tanhf(gihL[512 + t] + rr * (Ghh[512 + t] + bhh[512 + t]));
            out[259 + i * 256 + t] = (1.f - zz) * ncand + zz * Hacc[t];
        }
    }
}

// ============ epi1: disc layer-2 GEMV over 8 blocks ============
__global__ void k_epi1(const float* __restrict__ W2, const float* __restrict__ b2,
                       const float* __restrict__ d1r, const float* __restrict__ d1f,
                       float* __restrict__ l2buf) {
    __shared__ __align__(16) float lv[512];
    int b = blockIdx.x, t = threadIdx.x, l = t & 63, w = t >> 6;
    int br = b >> 2, q = b & 3;
    const float* d1 = br ? d1f : d1r;
    for (int j = t; j < 512; j += 256) { float v = d1[j]; lv[j] = v > 0.f ? v : 0.2f * v; }
    __syncthreads();
    const float4* l4 = (const float4*)lv;
    float4 va = l4[l], vb = l4[64 + l];
    for (int k = 0; k < 16; ++k) {
        int tr = q * 64 + w * 16 + k;
        const float4* wr = (const float4*)(W2 + (size_t)tr * 512);
        float acc = dot4(wr[l], va) + dot4(wr[64 + l], vb);
        acc = wave_reduce64(acc);
        if (l == 0) {
            float z = acc + b2[tr];
            l2buf[br * 256 + tr] = z > 0.f ? z : 0.2f * z;
        }
    }
}

// ============ epi2: final dots + sigmoid + mean tension + combine ============
__global__ void k_epi2(const float* __restrict__ W3, const float* __restrict__ b3,
                       const float* __restrict__ l2buf,
                       const float* __restrict__ outputs, const float* __restrict__ tensions,
                       float* __restrict__ out) {
    __shared__ float red[256];
    __shared__ float w[32];
    __shared__ float ts[32];
    int t = threadIdx.x;
    for (int p = 0; p < 2; ++p) {
        red[t] = l2buf[p * 256 + t] * W3[t];
        __syncthreads();
        for (int m = 128; m; m >>= 1) { if (t < m) red[t] += red[t + m]; __syncthreads(); }
        if (t == 0) out[257 + p] = 1.f / (1.f + expf(-(red[0] + b3[0])));
        __syncthreads();
    }
    if (t < 32) ts[t] = tensions[t];
    __syncthreads();
    if (t == 0) {
        float mx = ts[0];
        for (int i = 1; i < 32; ++i) mx = fmaxf(mx, ts[i]);
        float s = 0.f, mean = 0.f;
        for (int i = 0; i < 32; ++i) { float e = expf(ts[i] - mx); w[i] = e; s += e; mean += ts[i]; }
        float inv = 1.f / s;
        for (int i = 0; i < 32; ++i) w[i] *= inv;
        out[256] = mean * (1.f / 32.f);
    }
    __syncthreads();
    float c = 0.f;
    for (int i = 0; i < 32; ++i) c += w[i] * outputs[i * 256 + t];
    out[t] = c;
}

extern "C" void kernel_launch(void* const* d_in, const int* in_sizes, int n_in,
                              void* d_out, int out_size, void* d_ws, size_t ws_size,
                              hipStream_t stream) {
    const float* x     = (const float*)d_in[0];
    const float* noise = (const float*)d_in[1];
    const float* ch    = (const float*)d_in[2];
    const float* gW1   = (const float*)d_in[3];
    const float* gb1   = (const float*)d_in[4];
    const float* gW2   = (const float*)d_in[5];
    const float* gb2   = (const float*)d_in[6];
    const float* gW3   = (const float*)d_in[7];
    const float* gb3   = (const float*)d_in[8];
    const float* dW1   = (const float*)d_in[9];
    const float* db1   = (const float*)d_in[10];
    const float* dW2   = (const float*)d_in[11];
    const float* db2   = (const float*)d_in[12];
    const float* dW3   = (const float*)d_in[13];
    const float* db3   = (const float*)d_in[14];
    const float* eaW1  = (const float*)d_in[15];
    const float* eab1  = (const float*)d_in[16];
    const float* eaW2  = (const float*)d_in[17];
    const float* eab2  = (const float*)d_in[18];
    const float* egW1  = (const float*)d_in[19];
    const float* egb1  = (const float*)d_in[20];
    const float* egW2  = (const float*)d_in[21];
    const float* egb2  = (const float*)d_in[22];
    const float* Wih   = (const float*)d_in[23];
    const float* bih   = (const float*)d_in[24];
    const float* Whh   = (const float*)d_in[25];
    const float* bhh   = (const float*)d_in[26];
    const int*   step  = (const int*)d_in[27];

    float* out = (float*)d_out;
    float* ws  = (float*)d_ws;
    float* h1buf    = ws;                 // 256
    float* h2       = h1buf + 256;        // 512
    float* gs       = h2 + 512;           // 262144
    float* fmean    = gs + 262144;        // 2048
    float* outputs  = fmean + 2048;       // 8192
    float* tensions = outputs + 8192;     // 32
    float* d1r      = tensions + 32;      // 512
    float* d1f      = d1r + 512;          // 512
    float* l2buf    = d1f + 512;          // 512
    unsigned int* ctrl = (unsigned int*)(l2buf + 512);   // 64 uints

    k_gen_h1<<<64, 256, 0, stream>>>(x, noise, gW1, gb1, h1buf, ctrl);
    k_gen_h2<<<128, 256, 0, stream>>>(h1buf, gW2, gb2, h2);
    k_fused<<<GRIDF, 1024, 0, stream>>>(gW3, gb3, h2,
                                        dW1, db1, ch, step, x,
                                        eaW1, eab1, eaW2, eab2,
                                        egW1, egb1, egW2, egb2,
                                        Wih, bih, Whh, bhh,
                                        gs, fmean, ctrl,
                                        d1r, d1f, outputs, tensions, out);
    k_epi1<<<8, 256, 0, stream>>>(dW2, db2, d1r, d1f, l2buf);
    k_epi2<<<1, 256, 0, stream>>>(dW3, db3, l2buf, outputs, tensions, out);
}

// Round 10
// 325.230 us; speedup vs baseline: 2.1805x; 2.1805x over previous
//
#include <hip/hip_runtime.h>
#include <math.h>

#define N_CELLS 1024
#define HID     256
#define N_LOOP  32
#define FLAT    (N_CELLS*HID)   // 262144

typedef float f4 __attribute__((ext_vector_type(4)));

__device__ __forceinline__ float wave_reduce64(float v) {
    #pragma unroll
    for (int m = 32; m; m >>= 1) v += __shfl_xor(v, m);
    return v;
}
__device__ __forceinline__ float dot4(float4 a, float4 b) {
    return a.x*b.x + a.y*b.y + a.z*b.z + a.w*b.w;
}
__device__ __forceinline__ float dot4v(f4 a, float4 b) {
    return a.x*b.x + a.y*b.y + a.z*b.z + a.w*b.w;
}

// ============ h1 = relu(W1.gi + b1), wave-per-row (256 rows x 288) ============
__global__ void k_gen_h1(const float* __restrict__ x, const float* __restrict__ noise,
                         const float* __restrict__ W1, const float* __restrict__ b1,
                         float* __restrict__ h1) {
    __shared__ __align__(16) float gi[288];
    int t = threadIdx.x, l = t & 63, w = t >> 6;
    gi[t] = x[t];
    if (t < 32) gi[256 + t] = noise[t];
    __syncthreads();
    int j = blockIdx.x * 4 + w;
    const float4* wr = (const float4*)(W1 + j * 288);
    const float4* g4 = (const float4*)gi;
    float acc = dot4(wr[l], g4[l]);
    if (l < 8) acc += dot4(wr[64 + l], g4[64 + l]);
    acc = wave_reduce64(acc);
    if (l == 0) h1[j] = fmaxf(acc + b1[j], 0.f);
}

// ============ h2 = relu(W2.h1 + b2), wave-per-row (512 rows x 256) ============
__global__ void k_gen_h2(const float* __restrict__ h1, const float* __restrict__ W2,
                         const float* __restrict__ b2, float* __restrict__ h2) {
    int t = threadIdx.x, l = t & 63, w = t >> 6;
    int j = blockIdx.x * 4 + w;
    float acc = dot4(((const float4*)(W2 + j * 256))[l], ((const float4*)h1)[l]);
    acc = wave_reduce64(acc);
    if (l == 0) h2[j] = fmaxf(acc + b2[j], 0.f);
}

// ============ gen_states = W3.h2 + b3 — 4 rows/wave, NONTEMPORAL W3 stream ============
__global__ void k_gen_big(const float* __restrict__ W3, const float* __restrict__ b3,
                          const float* __restrict__ h2, float* __restrict__ gs) {
    int t = threadIdx.x, l = t & 63, w = t >> 6;
    int r0 = blockIdx.x * 16 + w * 4;
    const float4* h24 = (const float4*)h2;
    float4 ha = h24[l], hb = h24[64 + l];
    const f4* w0 = (const f4*)(W3 + (size_t)(r0 + 0) * 512);
    const f4* w1 = (const f4*)(W3 + (size_t)(r0 + 1) * 512);
    const f4* w2 = (const f4*)(W3 + (size_t)(r0 + 2) * 512);
    const f4* w3 = (const f4*)(W3 + (size_t)(r0 + 3) * 512);
    f4 A0 = __builtin_nontemporal_load(w0 + l);
    f4 B0 = __builtin_nontemporal_load(w0 + 64 + l);
    f4 A1 = __builtin_nontemporal_load(w1 + l);
    f4 B1 = __builtin_nontemporal_load(w1 + 64 + l);
    f4 A2 = __builtin_nontemporal_load(w2 + l);
    f4 B2 = __builtin_nontemporal_load(w2 + 64 + l);
    f4 A3 = __builtin_nontemporal_load(w3 + l);
    f4 B3 = __builtin_nontemporal_load(w3 + 64 + l);
    float s0 = dot4v(A0, ha) + dot4v(B0, hb);
    float s1 = dot4v(A1, ha) + dot4v(B1, hb);
    float s2 = dot4v(A2, ha) + dot4v(B2, hb);
    float s3 = dot4v(A3, ha) + dot4v(B3, hb);
    s0 = wave_reduce64(s0);
    s1 = wave_reduce64(s1);
    s2 = wave_reduce64(s2);
    s3 = wave_reduce64(s3);
    if (l == 0) {
        float4 bv = *(const float4*)(b3 + r0);
        float4 o; o.x = s0 + bv.x; o.y = s1 + bv.y; o.z = s2 + bv.z; o.w = s3 + bv.w;
        *(float4*)(gs + r0) = o;
    }
}

// ============ per-faction column means ============
__global__ void k_fmean(const float* __restrict__ gs, float* __restrict__ fmean) {
    __shared__ float part[4][64];
    int b = blockIdx.x, t = threadIdx.x;
    int f = b >> 2, q = b & 3;
    int c = q * 64 + (t & 63), rg = t >> 6;
    const float* base = gs + (size_t)(f * 128 + rg * 32) * 256 + c;
    float s0 = 0.f, s1 = 0.f, s2 = 0.f, s3 = 0.f;
    for (int i = 0; i < 32; i += 4) {
        s0 += base[(size_t)(i + 0) * 256];
        s1 += base[(size_t)(i + 1) * 256];
        s2 += base[(size_t)(i + 2) * 256];
        s3 += base[(size_t)(i + 3) * 256];
    }
    part[rg][t & 63] = (s0 + s1) + (s2 + s3);
    __syncthreads();
    if (t < 64) {
        float v = part[0][t] + part[1][t] + part[2][t] + part[3][t];
        fmean[f * 256 + q * 64 + t] = v * (1.f / 128.f);
    }
}

// ============ MEGA (512 thr, all 544 blocks co-resident): blocks 0..31 = chain,
//              blocks 32..543 = disc1 rows, NT dW1 stream, inline ncn ============
__global__ void k_mega(const float* __restrict__ dW1, const float* __restrict__ db1,
                       const float* __restrict__ gs, const float* __restrict__ ch,
                       const float* __restrict__ fmean, const int* __restrict__ step,
                       const float* __restrict__ x,
                       const float* __restrict__ eaW1, const float* __restrict__ eab1,
                       const float* __restrict__ eaW2, const float* __restrict__ eab2,
                       const float* __restrict__ egW1, const float* __restrict__ egb1,
                       const float* __restrict__ egW2, const float* __restrict__ egb2,
                       const float* __restrict__ Wih, const float* __restrict__ bih,
                       const float* __restrict__ Whh, const float* __restrict__ bhh,
                       float* __restrict__ d1r, float* __restrict__ d1f,
                       float* __restrict__ outputs, float* __restrict__ tensions,
                       float* __restrict__ out) {
    __shared__ float sR[8];
    __shared__ float sF[8];
    __shared__ __align__(16) float fmL[2048];    // 8 KB
    __shared__ __align__(16) float gmL[256];
    __shared__ __align__(16) float xh[512];      // [x | H]
    __shared__ __align__(16) float hag[256];
    __shared__ __align__(16) float outs[256];
    __shared__ float red[256];
    __shared__ float rzA[512];
    __shared__ float inb[256];
    __shared__ float hnb[256];
    __shared__ float tsh;
    int b = blockIdx.x, t = threadIdx.x, l = t & 63, w = t >> 6;
    bool deb = (*step > 5);

    if (b >= 32) {
        // ---- stage fmean + gm into LDS ----
        for (int i = t; i < 2048; i += 512) fmL[i] = fmean[i];
        __syncthreads();
        if (t < 256) {
            float g = 0.f;
            #pragma unroll
            for (int f = 0; f < 8; ++f) g += fmL[f * 256 + t];
            gmL[t] = g * 0.125f;
        }
        __syncthreads();
        // ---- disc1: dot dW1[row] vs real(ncn, inline) and fake(gs) ----
        int row = b - 32;
        const f4* w4 = (const f4*)(dW1 + (size_t)row * FLAT);
        const float4* g4 = (const float4*)gs;
        const float4* c4 = (const float4*)ch;
        float aR = 0.f, aF = 0.f;
        for (int i = t; i < FLAT / 4; i += 512) {
            int c = i >> 6, d4 = i & 63;
            f4 ww = __builtin_nontemporal_load(w4 + i);
            float4 gv = g4[i], cv = c4[i];
            float4 fmv = *(const float4*)(fmL + ((c >> 7) << 8) + d4 * 4);
            float4 v;
            v.x = 0.85f * gv.x + 0.15f * fmv.x;
            v.y = 0.85f * gv.y + 0.15f * fmv.y;
            v.z = 0.85f * gv.z + 0.15f * fmv.z;
            v.w = 0.85f * gv.w + 0.15f * fmv.w;
            if (deb && ((c & 127) < 32)) {
                float4 gm = *(const float4*)(gmL + d4 * 4);
                v.x = 0.85f * v.x + 0.15f * gm.x;
                v.y = 0.85f * v.y + 0.15f * gm.y;
                v.z = 0.85f * v.z + 0.15f * gm.z;
                v.w = 0.85f * v.w + 0.15f * gm.w;
            }
            float4 nc;
            nc.x = 0.7f * v.x + 0.3f * cv.x;
            nc.y = 0.7f * v.y + 0.3f * cv.y;
            nc.z = 0.7f * v.z + 0.3f * cv.z;
            nc.w = 0.7f * v.w + 0.3f * cv.w;
            aR += dot4v(ww, nc);
            aF += dot4v(ww, gv);
        }
        aR = wave_reduce64(aR);
        aF = wave_reduce64(aF);
        if (l == 0) { sR[w] = aR; sF[w] = aF; }
        __syncthreads();
        if (t < 8) {
            float r = sR[t], f = sF[t];
            #pragma unroll
            for (int m = 4; m; m >>= 1) { r += __shfl_xor(r, m); f += __shfl_xor(f, m); }
            if (t == 0) { d1r[row] = r + db1[row]; d1f[row] = f + db1[row]; }
        }
        return;
    }

    // ---------- chain role: sample i = b (8 waves) ----------
    int i = b;
    if (t < 256) {
        xh[t] = x[t];
        float g = gs[i * 256 + t];
        float gmv = 0.f;
        #pragma unroll
        for (int f = 0; f < 8; ++f) gmv += fmean[f * 256 + t];
        gmv *= 0.125f;
        float v = 0.85f * g + 0.15f * fmean[t];     // cells 0..31 are faction 0
        if (deb) v = 0.85f * v + 0.15f * gmv;
        xh[256 + t] = v;
    }
    __syncthreads();

    // ev layer 1: 8 waves x 32 neurons, wave-per-row 512-dot
    for (int k = 0; k < 32; ++k) {
        int j = w * 32 + k;
        const float* W = (j < 128) ? (eaW1 + (size_t)j * 512) : (egW1 + (size_t)(j - 128) * 512);
        const float4* w4 = (const float4*)W;
        const float4* v4 = (const float4*)xh;
        float acc = dot4(w4[l], v4[l]) + dot4(w4[64 + l], v4[64 + l]);
        acc = wave_reduce64(acc);
        if (l == 0) {
            float bias = (j < 128) ? eab1[j] : egb1[j - 128];
            hag[j] = fmaxf(acc + bias, 0.f);
        }
    }
    __syncthreads();

    // ev layer 2: 8 waves x 32 neurons; lanes 0-31 ea(+), 32-63 eg(-)
    for (int k = 0; k < 32; ++k) {
        int tr = w * 32 + k;
        int sl = l & 31;
        bool lo = (l < 32);
        const float4* wv4 = lo ? (const float4*)(eaW2 + (size_t)tr * 128)
                               : (const float4*)(egW2 + (size_t)tr * 128);
        const float4* h4 = (const float4*)(hag + (lo ? 0 : 128));
        float d_ = dot4(wv4[sl], h4[sl]);
        float acc = lo ? d_ : -d_;
        acc = wave_reduce64(acc);
        if (l == 0) {
            float o = acc + eab2[tr] - egb2[tr];
            outs[tr] = o;
            outputs[i * 256 + tr] = o;
        }
    }
    __syncthreads();

    // tension
    if (t < 256) red[t] = outs[t] * outs[t];
    __syncthreads();
    for (int m = 128; m; m >>= 1) { if (t < m && t + m < 256) red[t] += red[t + m]; __syncthreads(); }
    if (t == 0) { float tn = red[0] * (1.f / 256.f); tensions[i] = tn; tsh = tn; }
    __syncthreads();
    float tn = tsh;

    // GRU matvecs: 8 waves x 96 rows (768 rows)
    {
        float4 ov = ((const float4*)outs)[l];
        float4 Hv = ((const float4*)(xh + 256))[l];
        for (int k = 0; k < 96; ++k) {
            int u = w * 96 + k;
            const float* wr = Wih + (size_t)u * 257;
            float g0 = wr[4*l]*ov.x + wr[4*l+1]*ov.y + wr[4*l+2]*ov.z + wr[4*l+3]*ov.w;
            if (l == 0) g0 += wr[256] * tn;
            float4 wh = ((const float4*)(Whh + (size_t)u * 256))[l];
            float h0 = dot4(wh, Hv);
            if (u < 512) {
                float s = wave_reduce64(g0 + h0);
                if (l == 0) rzA[u] = s + bih[u] + bhh[u];
            } else {
                float sg = wave_reduce64(g0);
                float sh = wave_reduce64(h0);
                if (l == 0) { inb[u - 512] = sg + bih[u]; hnb[u - 512] = sh + bhh[u]; }
            }
        }
    }
    __syncthreads();

    // GRU finish
    if (t < 256) {
        float r = 1.f / (1.f + expf(-rzA[t]));
        float z = 1.f / (1.f + expf(-rzA[256 + t]));
        float nc = tanhf(inb[t] + r * hnb[t]);
        float Hd = xh[256 + t];
        out[259 + i * 256 + t] = (1.f - z) * nc + z * Hd;
    }
}

// ============ epi1: disc layer-2 GEMV over 8 blocks ============
__global__ void k_epi1(const float* __restrict__ W2, const float* __restrict__ b2,
                       const float* __restrict__ d1r, const float* __restrict__ d1f,
                       float* __restrict__ l2buf) {
    __shared__ __align__(16) float lv[512];
    int b = blockIdx.x, t = threadIdx.x, l = t & 63, w = t >> 6;
    int br = b >> 2, q = b & 3;
    const float* d1 = br ? d1f : d1r;
    for (int j = t; j < 512; j += 256) { float v = d1[j]; lv[j] = v > 0.f ? v : 0.2f * v; }
    __syncthreads();
    const float4* l4 = (const float4*)lv;
    float4 va = l4[l], vb = l4[64 + l];
    for (int k = 0; k < 16; ++k) {
        int tr = q * 64 + w * 16 + k;
        const float4* wr = (const float4*)(W2 + (size_t)tr * 512);
        float acc = dot4(wr[l], va) + dot4(wr[64 + l], vb);
        acc = wave_reduce64(acc);
        if (l == 0) {
            float z = acc + b2[tr];
            l2buf[br * 256 + tr] = z > 0.f ? z : 0.2f * z;
        }
    }
}

// ============ epi2: final dots + sigmoid + mean tension + combine ============
__global__ void k_epi2(const float* __restrict__ W3, const float* __restrict__ b3,
                       const float* __restrict__ l2buf,
                       const float* __restrict__ outputs, const float* __restrict__ tensions,
                       float* __restrict__ out) {
    __shared__ float red[256];
    __shared__ float w[32];
    __shared__ float ts[32];
    int t = threadIdx.x;
    for (int p = 0; p < 2; ++p) {
        red[t] = l2buf[p * 256 + t] * W3[t];
        __syncthreads();
        for (int m = 128; m; m >>= 1) { if (t < m) red[t] += red[t + m]; __syncthreads(); }
        if (t == 0) out[257 + p] = 1.f / (1.f + expf(-(red[0] + b3[0])));
        __syncthreads();
    }
    if (t < 32) ts[t] = tensions[t];
    __syncthreads();
    if (t == 0) {
        float mx = ts[0];
        for (int i = 1; i < 32; ++i) mx = fmaxf(mx, ts[i]);
        float s = 0.f, mean = 0.f;
        for (int i = 0; i < 32; ++i) { float e = expf(ts[i] - mx); w[i] = e; s += e; mean += ts[i]; }
        float inv = 1.f / s;
        for (int i = 0; i < 32; ++i) w[i] *= inv;
        out[256] = mean * (1.f / 32.f);
    }
    __syncthreads();
    float c = 0.f;
    for (int i = 0; i < 32; ++i) c += w[i] * outputs[i * 256 + t];
    out[t] = c;
}

extern "C" void kernel_launch(void* const* d_in, const int* in_sizes, int n_in,
                              void* d_out, int out_size, void* d_ws, size_t ws_size,
                              hipStream_t stream) {
    const float* x     = (const float*)d_in[0];
    const float* noise = (const float*)d_in[1];
    const float* ch    = (const float*)d_in[2];
    const float* gW1   = (const float*)d_in[3];
    const float* gb1   = (const float*)d_in[4];
    const float* gW2   = (const float*)d_in[5];
    const float* gb2   = (const float*)d_in[6];
    const float* gW3   = (const float*)d_in[7];
    const float* gb3   = (const float*)d_in[8];
    const float* dW1   = (const float*)d_in[9];
    const float* db1   = (const float*)d_in[10];
    const float* dW2   = (const float*)d_in[11];
    const float* db2   = (const float*)d_in[12];
    const float* dW3   = (const float*)d_in[13];
    const float* db3   = (const float*)d_in[14];
    const float* eaW1  = (const float*)d_in[15];
    const float* eab1  = (const float*)d_in[16];
    const float* eaW2  = (const float*)d_in[17];
    const float* eab2  = (const float*)d_in[18];
    const float* egW1  = (const float*)d_in[19];
    const float* egb1  = (const float*)d_in[20];
    const float* egW2  = (const float*)d_in[21];
    const float* egb2  = (const float*)d_in[22];
    const float* Wih   = (const float*)d_in[23];
    const float* bih   = (const float*)d_in[24];
    const float* Whh   = (const float*)d_in[25];
    const float* bhh   = (const float*)d_in[26];
    const int*   step  = (const int*)d_in[27];

    float* out = (float*)d_out;
    float* ws  = (float*)d_ws;
    float* h1buf    = ws;                 // 256
    float* h2       = h1buf + 256;        // 512
    float* gs       = h2 + 512;           // 262144
    float* fmean    = gs + 262144;        // 2048
    float* outputs  = fmean + 2048;       // 8192
    float* tensions = outputs + 8192;     // 32
    float* d1r      = tensions + 32;      // 512
    float* d1f      = d1r + 512;          // 512
    float* l2buf    = d1f + 512;          // 512

    k_gen_h1<<<64, 256, 0, stream>>>(x, noise, gW1, gb1, h1buf);
    k_gen_h2<<<128, 256, 0, stream>>>(h1buf, gW2, gb2, h2);
    k_gen_big<<<FLAT / 16, 256, 0, stream>>>(gW3, gb3, h2, gs);
    k_fmean<<<32, 256, 0, stream>>>(gs, fmean);
    k_mega<<<544, 512, 0, stream>>>(dW1, db1, gs, ch, fmean, step, x,
                                    eaW1, eab1, eaW2, eab2,
                                    egW1, egb1, egW2, egb2,
                                    Wih, bih, Whh, bhh,
                                    d1r, d1f, outputs, tensions, out);
    k_epi1<<<8, 256, 0, stream>>>(dW2, db2, d1r, d1f, l2buf);
    k_epi2<<<1, 256, 0, stream>>>(dW3, db3, l2buf, outputs, tensions, out);
}